// Round 7
// baseline (117.785 us; speedup 1.0000x reference)
//
#include <hip/hip_runtime.h>

// GMELoss3D: fused 3D Sobel edge-magnitude MSE on [2,2,128,128,128] fp32 volumes.
// R9: packed-FP32 (v_pk_*) — fold the Y/P volume pipelines into one v2f stream.
//   - R8 post-mortem: deferred-consume worked (50.8->45us, VALUBusy 47->54%)
//     but counter math shows ~270 VALU/plane vs ~120 nominal, and the nominal
//     stream computes IDENTICAL arithmetic twice (Y volume, P volume).
//   - Fix: ext_vector_type(2) float with Y in .x, P in .y. gfx950 has
//     full-rate packed fp32 (v_pk_fma_f32/v_pk_add_f32/v_pk_mul_f32):
//     one issue slot covers both volumes -> ~halves VALU issue count for
//     channel sums, ys/yd/ye, combos, and the edge-magnitude chain.
//     bpermutes stay 12/plane (DS pipe). sqrtf -> __builtin_amdgcn_sqrtf
//     (raw v_sqrt_f32, no libm fixup tail). cndmask-zeroing -> mask-multiply
//     (clamped-address loads are finite, so x*0 == 0 exactly).
//   - Everything else identical to R8: wave = one x-row, overlapped x-tiles
//     (3 tiles x 62 outputs), raw-destination prefetch consumed next
//     iteration (vmcnt(12) discipline), zero __syncthreads in z-loop,
//     unroll 6 (indices compile-time, rule #20), no launch_bounds clamp.
//
// Separable decomposition: s=[1,2,1], d=[-1,0,1], e=[1,1,1], y-first:
//   C0=s_y d_x  C1=d_y s_x  C2=s_y s_x  C3=e_y d_x  C4=d_y e_x  C5=e_y s_x
//   C6=s_y e_x ; z-combines in edge_mag. Signs irrelevant (squared).

namespace {

typedef float v2f __attribute__((ext_vector_type(2)));

constexpr int ZDIM = 128, YDIM = 128, XDIM = 128;   // (H, W, D); D contiguous
constexpr int TX = 64, TY = 4, ZC = 16;
constexpr int OTW = 62;                   // output columns per overlapped tile
constexpr int NXT = 3;                    // x-tiles: ceil(128/62)
constexpr int YX = YDIM * XDIM;           // z-plane stride (floats)
constexpr size_t CS = (size_t)ZDIM * YX;  // channel stride
constexpr float INV_N = 1.0f / 4194304.0f;

__device__ __forceinline__ float bperm(int addr, float v) {
  return __int_as_float(__builtin_amdgcn_ds_bpermute(addr, __float_as_int(v)));
}

__device__ __forceinline__ v2f vfma(v2f a, v2f b, v2f c) {
  return __builtin_elementwise_fma(a, b, c);
}

__device__ __forceinline__ v2f vsplat(float x) { v2f r = {x, x}; return r; }

// packed sum-of-squares of the 9 gradients (+eps), from 3 planes' combos
__device__ __forceinline__ v2f emag_ss(const v2f* __restrict__ Ca,
                                       const v2f* __restrict__ Cb,
                                       const v2f* __restrict__ Cc) {
  const v2f two = vsplat(2.0f);
  const v2f g1  = vfma(two, Cb[0], Ca[0] + Cc[0]);   // Sx
  const v2f g2  = vfma(two, Cb[1], Ca[1] + Cc[1]);   // Sy
  const v2f g3  = Cc[2] - Ca[2];                     // Sz
  const v2f Azx = vfma(two, Cb[3], Ca[3] + Cc[3]);   // s_z e_y d_x
  const v2f Azy = vfma(two, Cb[4], Ca[4] + Cc[4]);   // s_z d_y e_x
  const v2f Axz = Cc[5] - Ca[5];                     // d_z e_y s_x
  const v2f Axy = g2 - Cb[1];                        // e_z d_y s_x
  const v2f Ayx = g1 - Cb[0];                        // e_z s_y d_x
  const v2f Ayz = Cc[6] - Ca[6];                     // d_z s_y e_x
  const v2f g4 = Azx - Azy, g5 = Azx + Azy;          // Sd11, Sd12
  const v2f g6 = Axz - Axy, g7 = Axz + Axy;          // Sd21, Sd22
  const v2f g8 = Ayx - Ayz, g9 = Ayx + Ayz;          // Sd31, Sd32
  v2f s = vfma(g1, g1, vsplat(1e-12f));
  s = vfma(g2, g2, s); s = vfma(g3, g3, s);
  s = vfma(g4, g4, s); s = vfma(g5, g5, s);
  s = vfma(g6, g6, s); s = vfma(g7, g7, s);
  s = vfma(g8, g8, s); s = vfma(g9, g9, s);
  return s;
}

__global__ __launch_bounds__(256)
void gme_loss_kernel(const float* __restrict__ y,
                     const float* __restrict__ yp,
                     float* __restrict__ out) {
  const int lane = threadIdx.x;          // lane in wave == x within tile
  const int ty   = threadIdx.y;          // row within block (0..3); wave id
  const int tid  = ty * TX + lane;

  const int bx = blockIdx.x;             // 3 x-tiles * 32 y-tiles
  const int t  = bx % NXT;
  const int yt = bx / NXT;
  const int yy = yt * TY + ty;           // global row (wave-uniform)
  const int z0 = blockIdx.y * ZC;
  const int b  = blockIdx.z;

  const float* Y0 = y  + (size_t)b * 2 * CS;   // vol y, ch 0
  const float* Y1 = Y0 + CS;                   // vol y, ch 1
  const float* P0 = yp + (size_t)b * 2 * CS;   // vol yp, ch 0
  const float* P1 = P0 + CS;

  // overlapped tile: loads columns X0..X0+63, emits outputs at lanes 1..62
  const int  X0  = OTW * t - 1;
  const int  xg  = X0 + lane;
  const int  xgc = xg < 0 ? 0 : (xg > XDIM - 1 ? XDIM - 1 : xg);
  const bool xok = (unsigned)xg < (unsigned)XDIM;
  const bool eok = xok && (lane >= 1) && (lane <= OTW);
  const float xmask = xok ? 1.0f : 0.0f;   // loads are clamped => finite => *0 exact
  const float emask = eok ? 1.0f : 0.0f;

  const int vox = yy * XDIM + xgc;
  const bool okM0 = (yy > 0);            // wave-uniform
  const bool okP0 = (yy < YDIM - 1);

  // bpermute byte-addresses for x-1 / x+1 (clamped; edge lanes never emit)
  const int addrL = (lane > 0 ? lane - 1 : 0) << 2;
  const int addrR = (lane < TX - 1 ? lane + 1 : TX - 1) << 2;

  // RAW packed prefetch buffers — .x = Y volume, .y = P volume.
  // [0]=ch0 row y-1, [1]=ch1 row y-1, [2]=ch0 y, [3]=ch1 y, [4]=ch0 y+1, [5]=ch1 y+1
  v2f pf[2][6];
  v2f K[3][7] = {};                      // mod-3 per-plane packed combo pipeline
  float acc = 0.0f;

  auto loadRaw = [&](int buf, int zc) {
    const bool zok = (unsigned)zc < (unsigned)ZDIM;
    const int  zca = zok ? zc : 0;       // address-safe clamp (loads skipped)
    const int  o   = zca * YX + vox;
    v2f a0 = {0.f, 0.f}, a1 = {0.f, 0.f};
    if (zok && okM0) {                   // wave-uniform branch, 4 loads
      a0.x = Y0[o - XDIM]; a0.y = P0[o - XDIM];
      a1.x = Y1[o - XDIM]; a1.y = P1[o - XDIM];
    }
    v2f b0 = {0.f, 0.f}, b1 = {0.f, 0.f};
    if (zok) {                           // wave-uniform branch, 4 loads
      b0.x = Y0[o]; b0.y = P0[o];
      b1.x = Y1[o]; b1.y = P1[o];
    }
    v2f c0 = {0.f, 0.f}, c1 = {0.f, 0.f};
    if (zok && okP0) {                   // wave-uniform branch, 4 loads
      c0.x = Y0[o + XDIM]; c0.y = P0[o + XDIM];
      c1.x = Y1[o + XDIM]; c1.y = P1[o + XDIM];
    }
    pf[buf][0] = a0; pf[buf][1] = a1;
    pf[buf][2] = b0; pf[buf][3] = b1;
    pf[buf][4] = c0; pf[buf][5] = c1;
  };

  loadRaw(0, z0 - 1);                           // prologue: plane j=0

#pragma unroll 6
  for (int j = 0; j < ZC + 2; ++j) {            // 18 planes, zc = z0-1+j
    const int cur = j & 1;
    if (j < ZC + 1) loadRaw(cur ^ 1, z0 + j);   // issue next plane's 12 loads

    // consume pf[cur] (loaded LAST iteration -> only vmcnt(12) wait needed)
    const v2f* q = pf[cur];
    const v2f sm = q[0] + q[1];                 // channel sums (packed)
    const v2f sc = q[2] + q[3];
    const v2f sp = q[4] + q[5];

    const v2f tt = sm + sp;
    v2f ys = vfma(vsplat(2.0f), sc, tt);        // s_y
    v2f yd = sp - sm;                           // d_y
    v2f ye = tt + sc;                           // e_y
    ys *= xmask; yd *= xmask; ye *= xmask;      // zero out-of-volume columns

    v2f ysL, ysR, ydL, ydR, yeL, yeR;
    ysL.x = bperm(addrL, ys.x); ysL.y = bperm(addrL, ys.y);
    ysR.x = bperm(addrR, ys.x); ysR.y = bperm(addrR, ys.y);
    ydL.x = bperm(addrL, yd.x); ydL.y = bperm(addrL, yd.y);
    ydR.x = bperm(addrR, yd.x); ydR.y = bperm(addrR, yd.y);
    yeL.x = bperm(addrL, ye.x); yeL.y = bperm(addrL, ye.y);
    yeR.x = bperm(addrR, ye.x); yeR.y = bperm(addrR, ye.y);

    v2f* C = K[j % 3];
    const v2f tS = ysL + ysR, tD = ydL + ydR, tE = yeL + yeR;
    C[0] = ysR - ysL;                           // s_y d_x
    C[2] = vfma(vsplat(2.0f), ys, tS);          // s_y s_x
    C[6] = tS + ys;                             // s_y e_x
    C[1] = vfma(vsplat(2.0f), yd, tD);          // d_y s_x
    C[4] = tD + yd;                             // d_y e_x
    C[3] = yeR - yeL;                           // e_y d_x
    C[5] = vfma(vsplat(2.0f), ye, tE);          // e_y s_x

    if (j >= 2) {                               // emit output plane z0-3+j
      const v2f ss = emag_ss(K[(j + 1) % 3], K[(j + 2) % 3], C);
      const float my = __builtin_amdgcn_sqrtf(ss.x);
      const float mp = __builtin_amdgcn_sqrtf(ss.y);
      float d = 0.5f * (my - mp);               // half-mags (C=2)
      d *= emask;                               // gate non-emitting lanes
      acc = __builtin_fmaf(d, d, acc);
    }
  }

  // ---- block reduction (only sync in the kernel) ----
  __shared__ float red[4];
#pragma unroll
  for (int off = 32; off > 0; off >>= 1) acc += __shfl_down(acc, off);
  if (lane == 0) red[ty] = acc;                 // wave id == ty (TX==64)
  __syncthreads();
  if (tid == 0) {
    const float s = (red[0] + red[1] + red[2] + red[3]) * INV_N;
    atomicAdd(out, s);
  }
}

}  // namespace

extern "C" void kernel_launch(void* const* d_in, const int* in_sizes, int n_in,
                              void* d_out, int out_size, void* d_ws, size_t ws_size,
                              hipStream_t stream) {
  const float* y  = (const float*)d_in[0];
  const float* yp = (const float*)d_in[1];
  float* out = (float*)d_out;

  // d_out is poisoned before every launch: zero via memset node (graph-capturable)
  hipMemsetAsync(out, 0, sizeof(float), stream);

  dim3 block(TX, TY, 1);                        // 256 threads = 4 waves, 1 row each
  dim3 grid(NXT * (YDIM / TY),                  // 3 x-tiles * 32 y-tiles = 96
            ZDIM / ZC,                          // 8 z-chunks
            2);                                 // batch  => 1536 blocks
  gme_loss_kernel<<<grid, block, 0, stream>>>(y, yp, out);
}

// Round 8
// 115.266 us; speedup vs baseline: 1.0219x; 1.0219x over previous
//
#include <hip/hip_runtime.h>

// GMELoss3D: fused 3D Sobel edge-magnitude MSE on [2,2,128,128,128] fp32 volumes.
// R10: 3-deep prefetch ring — buy 2 plane-periods of load-latency cover.
//   - R9 post-mortem: packing halved VALU issue (VALUBusy 54->31%) but time
//     moved only 45->42us => VALU-issue exonerated; residual is EXPOSED LOAD
//     LATENCY. 1-plane slack (~250cy issue) vs ~470-900cy L2/HBM latency,
//     ~2.2 waves/SIMD resident (constant across all structures tried) =>
//     ~400cy exposed per plane.
//   - Fix: pf ring [2]->[3]. Iter j consumes plane j while j+1 AND j+2 are
//     in flight: latency budget doubles to 2 plane-periods; 24 loads/wave in
//     flight (6KB/wave). Cost +12 VGPR (60 -> ~80, far from 128 cliff).
//     All ring/K indices mod-3 => unroll 6 keeps them compile-time (rule #20).
//   - Everything else frozen from R9 (isolate one variable): packed v2f
//     (Y in .x, P in .y), wave = one x-row, overlapped x-tiles (3 x 62),
//     raw-destination prefetch, mask-mul edge handling, v_sqrt_f32,
//     zero __syncthreads in z-loop, no launch_bounds clamp.
//
// Separable decomposition: s=[1,2,1], d=[-1,0,1], e=[1,1,1], y-first:
//   C0=s_y d_x  C1=d_y s_x  C2=s_y s_x  C3=e_y d_x  C4=d_y e_x  C5=e_y s_x
//   C6=s_y e_x ; z-combines in emag_ss. Signs irrelevant (squared).

namespace {

typedef float v2f __attribute__((ext_vector_type(2)));

constexpr int ZDIM = 128, YDIM = 128, XDIM = 128;   // (H, W, D); D contiguous
constexpr int TX = 64, TY = 4, ZC = 16;
constexpr int OTW = 62;                   // output columns per overlapped tile
constexpr int NXT = 3;                    // x-tiles: ceil(128/62)
constexpr int YX = YDIM * XDIM;           // z-plane stride (floats)
constexpr size_t CS = (size_t)ZDIM * YX;  // channel stride
constexpr float INV_N = 1.0f / 4194304.0f;

__device__ __forceinline__ float bperm(int addr, float v) {
  return __int_as_float(__builtin_amdgcn_ds_bpermute(addr, __float_as_int(v)));
}

__device__ __forceinline__ v2f vfma(v2f a, v2f b, v2f c) {
  return __builtin_elementwise_fma(a, b, c);
}

__device__ __forceinline__ v2f vsplat(float x) { v2f r = {x, x}; return r; }

// packed sum-of-squares of the 9 gradients (+eps), from 3 planes' combos
__device__ __forceinline__ v2f emag_ss(const v2f* __restrict__ Ca,
                                       const v2f* __restrict__ Cb,
                                       const v2f* __restrict__ Cc) {
  const v2f two = vsplat(2.0f);
  const v2f g1  = vfma(two, Cb[0], Ca[0] + Cc[0]);   // Sx
  const v2f g2  = vfma(two, Cb[1], Ca[1] + Cc[1]);   // Sy
  const v2f g3  = Cc[2] - Ca[2];                     // Sz
  const v2f Azx = vfma(two, Cb[3], Ca[3] + Cc[3]);   // s_z e_y d_x
  const v2f Azy = vfma(two, Cb[4], Ca[4] + Cc[4]);   // s_z d_y e_x
  const v2f Axz = Cc[5] - Ca[5];                     // d_z e_y s_x
  const v2f Axy = g2 - Cb[1];                        // e_z d_y s_x
  const v2f Ayx = g1 - Cb[0];                        // e_z s_y d_x
  const v2f Ayz = Cc[6] - Ca[6];                     // d_z s_y e_x
  const v2f g4 = Azx - Azy, g5 = Azx + Azy;          // Sd11, Sd12
  const v2f g6 = Axz - Axy, g7 = Axz + Axy;          // Sd21, Sd22
  const v2f g8 = Ayx - Ayz, g9 = Ayx + Ayz;          // Sd31, Sd32
  v2f s = vfma(g1, g1, vsplat(1e-12f));
  s = vfma(g2, g2, s); s = vfma(g3, g3, s);
  s = vfma(g4, g4, s); s = vfma(g5, g5, s);
  s = vfma(g6, g6, s); s = vfma(g7, g7, s);
  s = vfma(g8, g8, s); s = vfma(g9, g9, s);
  return s;
}

__global__ __launch_bounds__(256)
void gme_loss_kernel(const float* __restrict__ y,
                     const float* __restrict__ yp,
                     float* __restrict__ out) {
  const int lane = threadIdx.x;          // lane in wave == x within tile
  const int ty   = threadIdx.y;          // row within block (0..3); wave id
  const int tid  = ty * TX + lane;

  const int bx = blockIdx.x;             // 3 x-tiles * 32 y-tiles
  const int t  = bx % NXT;
  const int yt = bx / NXT;
  const int yy = yt * TY + ty;           // global row (wave-uniform)
  const int z0 = blockIdx.y * ZC;
  const int b  = blockIdx.z;

  const float* Y0 = y  + (size_t)b * 2 * CS;   // vol y, ch 0
  const float* Y1 = Y0 + CS;                   // vol y, ch 1
  const float* P0 = yp + (size_t)b * 2 * CS;   // vol yp, ch 0
  const float* P1 = P0 + CS;

  // overlapped tile: loads columns X0..X0+63, emits outputs at lanes 1..62
  const int  X0  = OTW * t - 1;
  const int  xg  = X0 + lane;
  const int  xgc = xg < 0 ? 0 : (xg > XDIM - 1 ? XDIM - 1 : xg);
  const bool xok = (unsigned)xg < (unsigned)XDIM;
  const bool eok = xok && (lane >= 1) && (lane <= OTW);
  const float xmask = xok ? 1.0f : 0.0f;   // loads are clamped => finite => *0 exact
  const float emask = eok ? 1.0f : 0.0f;

  const int vox = yy * XDIM + xgc;
  const bool okM0 = (yy > 0);            // wave-uniform
  const bool okP0 = (yy < YDIM - 1);

  // bpermute byte-addresses for x-1 / x+1 (clamped; edge lanes never emit)
  const int addrL = (lane > 0 ? lane - 1 : 0) << 2;
  const int addrR = (lane < TX - 1 ? lane + 1 : TX - 1) << 2;

  // RAW packed prefetch RING (3 planes in flight) — .x = Y volume, .y = P.
  // [0]=ch0 row y-1, [1]=ch1 row y-1, [2]=ch0 y, [3]=ch1 y, [4]=ch0 y+1, [5]=ch1 y+1
  v2f pf[3][6];
  v2f K[3][7] = {};                      // mod-3 per-plane packed combo pipeline
  float acc = 0.0f;

  auto loadRaw = [&](int buf, int zc) {
    const bool zok = (unsigned)zc < (unsigned)ZDIM;
    const int  zca = zok ? zc : 0;       // address-safe clamp (loads skipped)
    const int  o   = zca * YX + vox;
    v2f a0 = {0.f, 0.f}, a1 = {0.f, 0.f};
    if (zok && okM0) {                   // wave-uniform branch, 4 loads
      a0.x = Y0[o - XDIM]; a0.y = P0[o - XDIM];
      a1.x = Y1[o - XDIM]; a1.y = P1[o - XDIM];
    }
    v2f b0 = {0.f, 0.f}, b1 = {0.f, 0.f};
    if (zok) {                           // wave-uniform branch, 4 loads
      b0.x = Y0[o]; b0.y = P0[o];
      b1.x = Y1[o]; b1.y = P1[o];
    }
    v2f c0 = {0.f, 0.f}, c1 = {0.f, 0.f};
    if (zok && okP0) {                   // wave-uniform branch, 4 loads
      c0.x = Y0[o + XDIM]; c0.y = P0[o + XDIM];
      c1.x = Y1[o + XDIM]; c1.y = P1[o + XDIM];
    }
    pf[buf][0] = a0; pf[buf][1] = a1;
    pf[buf][2] = b0; pf[buf][3] = b1;
    pf[buf][4] = c0; pf[buf][5] = c1;
  };

  // prologue: planes j=0 (zc=z0-1) and j=1 (zc=z0) into ring slots 0,1
  loadRaw(0, z0 - 1);
  loadRaw(1, z0);

#pragma unroll 6
  for (int j = 0; j < ZC + 2; ++j) {            // 18 planes, zc = z0-1+j
    // issue plane j+2 into ring slot (j+2)%3; planes j+1, j+2 stay in flight
    if (j < ZC) loadRaw((j + 2) % 3, z0 + 1 + j);

    // consume pf[j%3] (issued 2 iterations ago -> 2 plane-periods of cover)
    const v2f* q = pf[j % 3];
    const v2f sm = q[0] + q[1];                 // channel sums (packed)
    const v2f sc = q[2] + q[3];
    const v2f sp = q[4] + q[5];

    const v2f tt = sm + sp;
    v2f ys = vfma(vsplat(2.0f), sc, tt);        // s_y
    v2f yd = sp - sm;                           // d_y
    v2f ye = tt + sc;                           // e_y
    ys *= xmask; yd *= xmask; ye *= xmask;      // zero out-of-volume columns

    v2f ysL, ysR, ydL, ydR, yeL, yeR;
    ysL.x = bperm(addrL, ys.x); ysL.y = bperm(addrL, ys.y);
    ysR.x = bperm(addrR, ys.x); ysR.y = bperm(addrR, ys.y);
    ydL.x = bperm(addrL, yd.x); ydL.y = bperm(addrL, yd.y);
    ydR.x = bperm(addrR, yd.x); ydR.y = bperm(addrR, yd.y);
    yeL.x = bperm(addrL, ye.x); yeL.y = bperm(addrL, ye.y);
    yeR.x = bperm(addrR, ye.x); yeR.y = bperm(addrR, ye.y);

    v2f* C = K[j % 3];
    const v2f tS = ysL + ysR, tD = ydL + ydR, tE = yeL + yeR;
    C[0] = ysR - ysL;                           // s_y d_x
    C[2] = vfma(vsplat(2.0f), ys, tS);          // s_y s_x
    C[6] = tS + ys;                             // s_y e_x
    C[1] = vfma(vsplat(2.0f), yd, tD);          // d_y s_x
    C[4] = tD + yd;                             // d_y e_x
    C[3] = yeR - yeL;                           // e_y d_x
    C[5] = vfma(vsplat(2.0f), ye, tE);          // e_y s_x

    if (j >= 2) {                               // emit output plane z0-3+j
      const v2f ss = emag_ss(K[(j + 1) % 3], K[(j + 2) % 3], C);
      const float my = __builtin_amdgcn_sqrtf(ss.x);
      const float mp = __builtin_amdgcn_sqrtf(ss.y);
      float d = 0.5f * (my - mp);               // half-mags (C=2)
      d *= emask;                               // gate non-emitting lanes
      acc = __builtin_fmaf(d, d, acc);
    }
  }

  // ---- block reduction (only sync in the kernel) ----
  __shared__ float red[4];
#pragma unroll
  for (int off = 32; off > 0; off >>= 1) acc += __shfl_down(acc, off);
  if (lane == 0) red[ty] = acc;                 // wave id == ty (TX==64)
  __syncthreads();
  if (tid == 0) {
    const float s = (red[0] + red[1] + red[2] + red[3]) * INV_N;
    atomicAdd(out, s);
  }
}

}  // namespace

extern "C" void kernel_launch(void* const* d_in, const int* in_sizes, int n_in,
                              void* d_out, int out_size, void* d_ws, size_t ws_size,
                              hipStream_t stream) {
  const float* y  = (const float*)d_in[0];
  const float* yp = (const float*)d_in[1];
  float* out = (float*)d_out;

  // d_out is poisoned before every launch: zero via memset node (graph-capturable)
  hipMemsetAsync(out, 0, sizeof(float), stream);

  dim3 block(TX, TY, 1);                        // 256 threads = 4 waves, 1 row each
  dim3 grid(NXT * (YDIM / TY),                  // 3 x-tiles * 32 y-tiles = 96
            ZDIM / ZC,                          // 8 z-chunks
            2);                                 // batch  => 1536 blocks
  gme_loss_kernel<<<grid, block, 0, stream>>>(y, yp, out);
}

// Round 9
// 114.805 us; speedup vs baseline: 1.0260x; 1.0040x over previous
//
#include <hip/hip_runtime.h>

// GMELoss3D: fused 3D Sobel edge-magnitude MSE on [2,2,128,128,128] fp32 volumes.
// R11: BRANCHLESS loads — make the prefetch ring real in the ISA.
//   - R8/R9/R10 post-mortem: all structures converge to ~43us; VALU-halving
//     (R9) and ring-deepening (R10) both null. Per-plane period ~1900cy vs
//     ~250cy issue. Diagnosis: loadRaw's wave-uniform BRANCHES around the
//     loads make outstanding-VMEM path-dependent => waitcnt pass must be
//     conservative (~vmcnt(0)) at every consume => every plane eats the
//     full loaded HBM-miss latency; declared ring depth never reaches ISA.
//   - Fix: 12 loads per plane UNCONDITIONAL from clamped addresses
//     (y-clamped row bases voxM/voxC/voxP, z-clamped zca); boundary
//     correctness moved to consume-time value masks (wave-uniform mm/mp,
//     per-plane fz) multiplied into channel sums — clamped loads are finite
//     so x*0 is exact. No if(j<ZC) issue-guard either (clamped zc; ~2 wasted
//     L2-warm planes per block). The unrolled z-loop is now straight-line =>
//     compiler statically counts 24 outstanding => s_waitcnt vmcnt(24) at
//     consume => depth-3 ring active: HBM misses get 2 plane-periods.
//   - Masks at CONSUME, raw values at LOAD (R7's lesson intact).
//   - Frozen: packed v2f (Y=.x, P=.y), wave = one x-row, overlapped x-tiles
//     (3 x 62), bpermute x+-1, v_sqrt_f32, zero __syncthreads in z-loop,
//     unroll 6 (mod-3 indices compile-time, rule #20), no launch_bounds clamp.
//
// Separable decomposition: s=[1,2,1], d=[-1,0,1], e=[1,1,1], y-first:
//   C0=s_y d_x  C1=d_y s_x  C2=s_y s_x  C3=e_y d_x  C4=d_y e_x  C5=e_y s_x
//   C6=s_y e_x ; z-combines in emag_ss. Signs irrelevant (squared).

namespace {

typedef float v2f __attribute__((ext_vector_type(2)));

constexpr int ZDIM = 128, YDIM = 128, XDIM = 128;   // (H, W, D); D contiguous
constexpr int TX = 64, TY = 4, ZC = 16;
constexpr int OTW = 62;                   // output columns per overlapped tile
constexpr int NXT = 3;                    // x-tiles: ceil(128/62)
constexpr int YX = YDIM * XDIM;           // z-plane stride (floats)
constexpr size_t CS = (size_t)ZDIM * YX;  // channel stride
constexpr float INV_N = 1.0f / 4194304.0f;

__device__ __forceinline__ float bperm(int addr, float v) {
  return __int_as_float(__builtin_amdgcn_ds_bpermute(addr, __float_as_int(v)));
}

__device__ __forceinline__ v2f vfma(v2f a, v2f b, v2f c) {
  return __builtin_elementwise_fma(a, b, c);
}

__device__ __forceinline__ v2f vsplat(float x) { v2f r = {x, x}; return r; }

// packed sum-of-squares of the 9 gradients (+eps), from 3 planes' combos
__device__ __forceinline__ v2f emag_ss(const v2f* __restrict__ Ca,
                                       const v2f* __restrict__ Cb,
                                       const v2f* __restrict__ Cc) {
  const v2f two = vsplat(2.0f);
  const v2f g1  = vfma(two, Cb[0], Ca[0] + Cc[0]);   // Sx
  const v2f g2  = vfma(two, Cb[1], Ca[1] + Cc[1]);   // Sy
  const v2f g3  = Cc[2] - Ca[2];                     // Sz
  const v2f Azx = vfma(two, Cb[3], Ca[3] + Cc[3]);   // s_z e_y d_x
  const v2f Azy = vfma(two, Cb[4], Ca[4] + Cc[4]);   // s_z d_y e_x
  const v2f Axz = Cc[5] - Ca[5];                     // d_z e_y s_x
  const v2f Axy = g2 - Cb[1];                        // e_z d_y s_x
  const v2f Ayx = g1 - Cb[0];                        // e_z s_y d_x
  const v2f Ayz = Cc[6] - Ca[6];                     // d_z s_y e_x
  const v2f g4 = Azx - Azy, g5 = Azx + Azy;          // Sd11, Sd12
  const v2f g6 = Axz - Axy, g7 = Axz + Axy;          // Sd21, Sd22
  const v2f g8 = Ayx - Ayz, g9 = Ayx + Ayz;          // Sd31, Sd32
  v2f s = vfma(g1, g1, vsplat(1e-12f));
  s = vfma(g2, g2, s); s = vfma(g3, g3, s);
  s = vfma(g4, g4, s); s = vfma(g5, g5, s);
  s = vfma(g6, g6, s); s = vfma(g7, g7, s);
  s = vfma(g8, g8, s); s = vfma(g9, g9, s);
  return s;
}

__global__ __launch_bounds__(256)
void gme_loss_kernel(const float* __restrict__ y,
                     const float* __restrict__ yp,
                     float* __restrict__ out) {
  const int lane = threadIdx.x;          // lane in wave == x within tile
  const int ty   = threadIdx.y;          // row within block (0..3); wave id
  const int tid  = ty * TX + lane;

  const int bx = blockIdx.x;             // 3 x-tiles * 32 y-tiles
  const int t  = bx % NXT;
  const int yt = bx / NXT;
  const int yy = yt * TY + ty;           // global row (wave-uniform)
  const int z0 = blockIdx.y * ZC;
  const int b  = blockIdx.z;

  const float* Y0 = y  + (size_t)b * 2 * CS;   // vol y, ch 0
  const float* Y1 = Y0 + CS;                   // vol y, ch 1
  const float* P0 = yp + (size_t)b * 2 * CS;   // vol yp, ch 0
  const float* P1 = P0 + CS;

  // overlapped tile: loads columns X0..X0+63, emits outputs at lanes 1..62
  const int  X0  = OTW * t - 1;
  const int  xg  = X0 + lane;
  const int  xgc = xg < 0 ? 0 : (xg > XDIM - 1 ? XDIM - 1 : xg);
  const bool xok = (unsigned)xg < (unsigned)XDIM;
  const bool eok = xok && (lane >= 1) && (lane <= OTW);
  const float xmask = xok ? 1.0f : 0.0f;   // clamped loads finite => *0 exact
  const float emask = eok ? 1.0f : 0.0f;

  // y-clamped row bases (wave-uniform) + value masks for clamped rows
  const int yM = yy > 0 ? yy - 1 : 0;
  const int yP = yy < YDIM - 1 ? yy + 1 : YDIM - 1;
  const int voxM = yM * XDIM + xgc;
  const int voxC = yy * XDIM + xgc;
  const int voxP = yP * XDIM + xgc;
  const float mm = (yy > 0) ? 1.0f : 0.0f;
  const float mp = (yy < YDIM - 1) ? 1.0f : 0.0f;

  // bpermute byte-addresses for x-1 / x+1 (clamped; edge lanes never emit)
  const int addrL = (lane > 0 ? lane - 1 : 0) << 2;
  const int addrR = (lane < TX - 1 ? lane + 1 : TX - 1) << 2;

  // RAW packed prefetch RING (3 planes in flight) — .x = Y volume, .y = P.
  // [0]=ch0 row y-1, [1]=ch1 row y-1, [2]=ch0 y, [3]=ch1 y, [4]=ch0 y+1, [5]=ch1 y+1
  v2f pf[3][6];
  v2f K[3][7] = {};                      // mod-3 per-plane packed combo pipeline
  float acc = 0.0f;

  // fully unconditional: 12 loads, clamped z, no branches => static vmcnt
  auto loadRaw = [&](int buf, int zc) {
    const int zca = zc < 0 ? 0 : (zc > ZDIM - 1 ? ZDIM - 1 : zc);
    const int o   = zca * YX;
    v2f a0, a1, b0, b1, c0, c1;
    a0.x = Y0[o + voxM]; a0.y = P0[o + voxM];
    a1.x = Y1[o + voxM]; a1.y = P1[o + voxM];
    b0.x = Y0[o + voxC]; b0.y = P0[o + voxC];
    b1.x = Y1[o + voxC]; b1.y = P1[o + voxC];
    c0.x = Y0[o + voxP]; c0.y = P0[o + voxP];
    c1.x = Y1[o + voxP]; c1.y = P1[o + voxP];
    pf[buf][0] = a0; pf[buf][1] = a1;
    pf[buf][2] = b0; pf[buf][3] = b1;
    pf[buf][4] = c0; pf[buf][5] = c1;
  };

  // prologue: planes j=0 (zc=z0-1) and j=1 (zc=z0) into ring slots 0,1
  loadRaw(0, z0 - 1);
  loadRaw(1, z0);

#pragma unroll 6
  for (int j = 0; j < ZC + 2; ++j) {            // 18 planes, zc = z0-1+j
    // issue plane j+2 unconditionally (z-clamped; tail planes unread/warm)
    loadRaw((j + 2) % 3, z0 + 1 + j);

    // consume pf[j%3] (issued 2 iterations ago => vmcnt(24) cover, counted)
    const int   zc = z0 - 1 + j;
    const float fz = ((unsigned)zc < (unsigned)ZDIM) ? 1.0f : 0.0f;
    const v2f* q = pf[j % 3];
    const v2f sm = (q[0] + q[1]) * vsplat(fz * mm);   // channel sums, masked
    const v2f sc = (q[2] + q[3]) * vsplat(fz);
    const v2f sp = (q[4] + q[5]) * vsplat(fz * mp);

    const v2f tt = sm + sp;
    v2f ys = vfma(vsplat(2.0f), sc, tt);        // s_y
    v2f yd = sp - sm;                           // d_y
    v2f ye = tt + sc;                           // e_y
    ys *= xmask; yd *= xmask; ye *= xmask;      // zero out-of-volume columns

    v2f ysL, ysR, ydL, ydR, yeL, yeR;
    ysL.x = bperm(addrL, ys.x); ysL.y = bperm(addrL, ys.y);
    ysR.x = bperm(addrR, ys.x); ysR.y = bperm(addrR, ys.y);
    ydL.x = bperm(addrL, yd.x); ydL.y = bperm(addrL, yd.y);
    ydR.x = bperm(addrR, yd.x); ydR.y = bperm(addrR, yd.y);
    yeL.x = bperm(addrL, ye.x); yeL.y = bperm(addrL, ye.y);
    yeR.x = bperm(addrR, ye.x); yeR.y = bperm(addrR, ye.y);

    v2f* C = K[j % 3];
    const v2f tS = ysL + ysR, tD = ydL + ydR, tE = yeL + yeR;
    C[0] = ysR - ysL;                           // s_y d_x
    C[2] = vfma(vsplat(2.0f), ys, tS);          // s_y s_x
    C[6] = tS + ys;                             // s_y e_x
    C[1] = vfma(vsplat(2.0f), yd, tD);          // d_y s_x
    C[4] = tD + yd;                             // d_y e_x
    C[3] = yeR - yeL;                           // e_y d_x
    C[5] = vfma(vsplat(2.0f), ye, tE);          // e_y s_x

    if (j >= 2) {                               // emit output plane z0-3+j
      const v2f ss = emag_ss(K[(j + 1) % 3], K[(j + 2) % 3], C);
      const float my = __builtin_amdgcn_sqrtf(ss.x);
      const float mp2 = __builtin_amdgcn_sqrtf(ss.y);
      float d = 0.5f * (my - mp2);              // half-mags (C=2)
      d *= emask;                               // gate non-emitting lanes
      acc = __builtin_fmaf(d, d, acc);
    }
  }

  // ---- block reduction (only sync in the kernel) ----
  __shared__ float red[4];
#pragma unroll
  for (int off = 32; off > 0; off >>= 1) acc += __shfl_down(acc, off);
  if (lane == 0) red[ty] = acc;                 // wave id == ty (TX==64)
  __syncthreads();
  if (tid == 0) {
    const float s = (red[0] + red[1] + red[2] + red[3]) * INV_N;
    atomicAdd(out, s);
  }
}

}  // namespace

extern "C" void kernel_launch(void* const* d_in, const int* in_sizes, int n_in,
                              void* d_out, int out_size, void* d_ws, size_t ws_size,
                              hipStream_t stream) {
  const float* y  = (const float*)d_in[0];
  const float* yp = (const float*)d_in[1];
  float* out = (float*)d_out;

  // d_out is poisoned before every launch: zero via memset node (graph-capturable)
  hipMemsetAsync(out, 0, sizeof(float), stream);

  dim3 block(TX, TY, 1);                        // 256 threads = 4 waves, 1 row each
  dim3 grid(NXT * (YDIM / TY),                  // 3 x-tiles * 32 y-tiles = 96
            ZDIM / ZC,                          // 8 z-chunks
            2);                                 // batch  => 1536 blocks
  gme_loss_kernel<<<grid, block, 0, stream>>>(y, yp, out);
}

// Round 10
// 107.242 us; speedup vs baseline: 1.0983x; 1.0705x over previous
//
#include <hip/hip_runtime.h>

// GMELoss3D: fused 3D Sobel edge-magnitude MSE on [2,2,128,128,128] fp32 volumes.
// R12: full-row waves + float2 (dwordx2) loads + 512 fat co-resident blocks.
//   - R2..R11 post-mortem: five distinct structures all converge to ~40-45us
//     (fetch near-ideal 80MB, VALU 31%, BW 2TB/s, occ ~25%, 0 conflicts,
//     0 spills). Per-block ~13us, ~1500cy/plane/wave vs ~300cy issue, ~1.9
//     waves/SIMD regardless of supply. Surviving suspects: per-block dispatch
//     pacing (dur ~= nblocks x ~30ns in every non-spill round), per-wave VMEM
//     issue economics (12 tiny 256B/wave loads per plane), x-overlap waste.
//   - This round attacks all three: wave = one FULL y-row, lane holds 2
//     x-columns loaded as one dwordx2 (512B/wave/load, half the loads per
//     output, no x-tiling -> no overlap waste, x-neighbors only at lane
//     seams: 6 bperms/output, halved); grid 1536 -> 512 blocks (32 y-tiles x
//     8 z x 2 b), ALL co-resident at t=0 (2 blocks/CU) -> dispatch pacing
//     eliminated. Kept: branchless clamped loads (R11), consume-time value
//     masks, raw-destination ring-3 prefetch, no __syncthreads in z-loop.
//   - Register economy: combo pipeline K stored mod-2 (only planes j-2, j-1;
//     current plane in temps) — K[2][7] x 2 vols, float2-over-x. Ring
//     pf[3][12] float2. Est ~180 VGPR -> 2 waves/SIMD cap == supply.
//   - unroll 6 (lcm of ring mod-3 and K mod-2) keeps all indices static.
//
// Separable decomposition: s=[1,2,1], d=[-1,0,1], e=[1,1,1], y-first:
//   C0=s_y d_x  C1=d_y s_x  C2=s_y s_x  C3=e_y d_x  C4=d_y e_x  C5=e_y s_x
//   C6=s_y e_x ; z-combines in emag_ss. Signs irrelevant (squared).

namespace {

typedef float v2f __attribute__((ext_vector_type(2)));

constexpr int ZDIM = 128, YDIM = 128, XDIM = 128;   // (H, W, D); D contiguous
constexpr int TX = 64, TY = 4, ZC = 16;
constexpr int XW  = XDIM / 2;             // 64 float2 per row (lane i: x=2i,2i+1)
constexpr int YX2 = YDIM * XW;            // float2 per z-plane
constexpr size_t CS2 = (size_t)ZDIM * YX2;  // channel stride in float2
constexpr float INV_N = 1.0f / 4194304.0f;

__device__ __forceinline__ float bperm(int addr, float v) {
  return __int_as_float(__builtin_amdgcn_ds_bpermute(addr, __float_as_int(v)));
}

__device__ __forceinline__ v2f vfma(v2f a, v2f b, v2f c) {
  return __builtin_elementwise_fma(a, b, c);
}

__device__ __forceinline__ v2f vsplat(float x) { v2f r = {x, x}; return r; }

// packed (over 2 x-columns) sum-of-squares of the 9 gradients (+eps)
__device__ __forceinline__ v2f emag_ss(const v2f* __restrict__ Ca,
                                       const v2f* __restrict__ Cb,
                                       const v2f* __restrict__ Cc) {
  const v2f two = vsplat(2.0f);
  const v2f g1  = vfma(two, Cb[0], Ca[0] + Cc[0]);   // Sx
  const v2f g2  = vfma(two, Cb[1], Ca[1] + Cc[1]);   // Sy
  const v2f g3  = Cc[2] - Ca[2];                     // Sz
  const v2f Azx = vfma(two, Cb[3], Ca[3] + Cc[3]);   // s_z e_y d_x
  const v2f Azy = vfma(two, Cb[4], Ca[4] + Cc[4]);   // s_z d_y e_x
  const v2f Axz = Cc[5] - Ca[5];                     // d_z e_y s_x
  const v2f Axy = g2 - Cb[1];                        // e_z d_y s_x
  const v2f Ayx = g1 - Cb[0];                        // e_z s_y d_x
  const v2f Ayz = Cc[6] - Ca[6];                     // d_z s_y e_x
  const v2f g4 = Azx - Azy, g5 = Azx + Azy;          // Sd11, Sd12
  const v2f g6 = Axz - Axy, g7 = Axz + Axy;          // Sd21, Sd22
  const v2f g8 = Ayx - Ayz, g9 = Ayx + Ayz;          // Sd31, Sd32
  v2f s = vfma(g1, g1, vsplat(1e-12f));
  s = vfma(g2, g2, s); s = vfma(g3, g3, s);
  s = vfma(g4, g4, s); s = vfma(g5, g5, s);
  s = vfma(g6, g6, s); s = vfma(g7, g7, s);
  s = vfma(g8, g8, s); s = vfma(g9, g9, s);
  return s;
}

__global__ __launch_bounds__(256)
void gme_loss_kernel(const float* __restrict__ y,
                     const float* __restrict__ yp,
                     float* __restrict__ out) {
  const int lane = threadIdx.x;          // lane i covers x = 2i, 2i+1 (full row)
  const int ty   = threadIdx.y;          // row within block (0..3); wave id
  const int tid  = ty * TX + lane;

  const int yy = blockIdx.x * TY + ty;   // global row 0..127 (wave-uniform)
  const int z0 = blockIdx.y * ZC;
  const int b  = blockIdx.z;

  const v2f* Y0 = (const v2f*)y  + (size_t)b * 2 * CS2;   // vol y, ch 0
  const v2f* Y1 = Y0 + CS2;                               // vol y, ch 1
  const v2f* P0 = (const v2f*)yp + (size_t)b * 2 * CS2;   // vol yp, ch 0
  const v2f* P1 = P0 + CS2;

  // y-clamped row bases (wave-uniform rows) + value masks for clamped rows
  const int yM = yy > 0 ? yy - 1 : 0;
  const int yP = yy < YDIM - 1 ? yy + 1 : YDIM - 1;
  const int oM = yM * XW + lane;
  const int oC = yy * XW + lane;
  const int oP = yP * XW + lane;
  const float mm = (yy > 0) ? 1.0f : 0.0f;
  const float mp = (yy < YDIM - 1) ? 1.0f : 0.0f;

  // lane-seam neighbor exchange: prev lane's x1 (.y), next lane's x0 (.x)
  const int addrL = (lane > 0 ? lane - 1 : 0) << 2;
  const int addrR = (lane < TX - 1 ? lane + 1 : TX - 1) << 2;
  const float lz = (lane == 0) ? 0.0f : 1.0f;        // x=-1 zero-pad
  const float rz = (lane == TX - 1) ? 0.0f : 1.0f;   // x=128 zero-pad

  // RAW prefetch RING, 3 planes in flight; each entry = float2 of 2 x-cols.
  // [0]Y0m [1]Y1m [2]P0m [3]P1m [4]Y0c [5]Y1c [6]P0c [7]P1c [8]Y0p [9]Y1p [10]P0p [11]P1p
  v2f pf[3][12];
  v2f KY[2][7], KP[2][7];                // mod-2 combo pipeline (j-2, j-1)
  v2f accv = {0.0f, 0.0f};

  // fully branchless: 12 dwordx2 loads, clamped z => static vmcnt counting
  auto loadRaw = [&](int buf, int zc) {
    const int zca = zc < 0 ? 0 : (zc > ZDIM - 1 ? ZDIM - 1 : zc);
    const int o   = zca * YX2;
    pf[buf][0]  = Y0[o + oM]; pf[buf][1]  = Y1[o + oM];
    pf[buf][2]  = P0[o + oM]; pf[buf][3]  = P1[o + oM];
    pf[buf][4]  = Y0[o + oC]; pf[buf][5]  = Y1[o + oC];
    pf[buf][6]  = P0[o + oC]; pf[buf][7]  = P1[o + oC];
    pf[buf][8]  = Y0[o + oP]; pf[buf][9]  = Y1[o + oP];
    pf[buf][10] = P0[o + oP]; pf[buf][11] = P1[o + oP];
  };

  // x-combine: from quantity q (v2f over x) build left/right neighbor vectors
  auto combos = [&](v2f ys, v2f yd, v2f ye, v2f* __restrict__ C) {
    const float ysl = bperm(addrL, ys.y) * lz, ysr = bperm(addrR, ys.x) * rz;
    const float ydl = bperm(addrL, yd.y) * lz, ydr = bperm(addrR, yd.x) * rz;
    const float yel = bperm(addrL, ye.y) * lz, yer = bperm(addrR, ye.x) * rz;
    const v2f ysL = {ysl, ys.x}, ysR = {ys.y, ysr};
    const v2f ydL = {ydl, yd.x}, ydR = {yd.y, ydr};
    const v2f yeL = {yel, ye.x}, yeR = {ye.y, yer};
    const v2f tS = ysL + ysR, tD = ydL + ydR, tE = yeL + yeR;
    C[0] = ysR - ysL;                           // s_y d_x
    C[2] = vfma(vsplat(2.0f), ys, tS);          // s_y s_x
    C[6] = tS + ys;                             // s_y e_x
    C[1] = vfma(vsplat(2.0f), yd, tD);          // d_y s_x
    C[4] = tD + yd;                             // d_y e_x
    C[3] = yeR - yeL;                           // e_y d_x
    C[5] = vfma(vsplat(2.0f), ye, tE);          // e_y s_x
  };

  // prologue: planes j=0 (zc=z0-1) and j=1 (zc=z0) into ring slots 0,1
  loadRaw(0, z0 - 1);
  loadRaw(1, z0);

#pragma unroll 6
  for (int j = 0; j < ZC + 2; ++j) {            // 18 planes, zc = z0-1+j
    loadRaw((j + 2) % 3, z0 + 1 + j);           // issue plane j+2 (z-clamped)

    // consume pf[j%3] (issued 2 iterations ago => counted-vmcnt cover)
    const int   zc = z0 - 1 + j;
    const float fz = ((unsigned)zc < (unsigned)ZDIM) ? 1.0f : 0.0f;
    const v2f* q = pf[j % 3];
    const v2f smY = (q[0] + q[1])  * vsplat(fz * mm);   // ch-sums, masked
    const v2f smP = (q[2] + q[3])  * vsplat(fz * mm);
    const v2f scY = (q[4] + q[5])  * vsplat(fz);
    const v2f scP = (q[6] + q[7])  * vsplat(fz);
    const v2f spY = (q[8] + q[9])  * vsplat(fz * mp);
    const v2f spP = (q[10] + q[11]) * vsplat(fz * mp);

    v2f Cy[7], Cp[7];
    {
      const v2f tt = smY + spY;
      combos(vfma(vsplat(2.0f), scY, tt), spY - smY, tt + scY, Cy);
    }
    {
      const v2f tt = smP + spP;
      combos(vfma(vsplat(2.0f), scP, tt), spP - smP, tt + scP, Cp);
    }

    if (j >= 2) {                               // emit output plane z0-2+j-? = z0+j-2
      const v2f ssY = emag_ss(KY[j % 2], KY[(j + 1) % 2], Cy);
      const v2f ssP = emag_ss(KP[j % 2], KP[(j + 1) % 2], Cp);
      v2f d;
      d.x = 0.5f * (__builtin_amdgcn_sqrtf(ssY.x) - __builtin_amdgcn_sqrtf(ssP.x));
      d.y = 0.5f * (__builtin_amdgcn_sqrtf(ssY.y) - __builtin_amdgcn_sqrtf(ssP.y));
      accv = vfma(d, d, accv);
    }

    // shift pipeline: slot j%2 (held plane j-2) now takes plane j
#pragma unroll
    for (int k = 0; k < 7; ++k) { KY[j % 2][k] = Cy[k]; KP[j % 2][k] = Cp[k]; }
  }

  // ---- block reduction (only sync in the kernel) ----
  __shared__ float red[4];
  float acc = accv.x + accv.y;
#pragma unroll
  for (int off = 32; off > 0; off >>= 1) acc += __shfl_down(acc, off);
  if (lane == 0) red[ty] = acc;                 // wave id == ty (TX==64)
  __syncthreads();
  if (tid == 0) {
    const float s = (red[0] + red[1] + red[2] + red[3]) * INV_N;
    atomicAdd(out, s);
  }
}

}  // namespace

extern "C" void kernel_launch(void* const* d_in, const int* in_sizes, int n_in,
                              void* d_out, int out_size, void* d_ws, size_t ws_size,
                              hipStream_t stream) {
  const float* y  = (const float*)d_in[0];
  const float* yp = (const float*)d_in[1];
  float* out = (float*)d_out;

  // d_out is poisoned before every launch: zero via memset node (graph-capturable)
  hipMemsetAsync(out, 0, sizeof(float), stream);

  dim3 block(TX, TY, 1);                        // 256 threads = 4 full-row waves
  dim3 grid(YDIM / TY,                          // 32 y-tiles
            ZDIM / ZC,                          // 8 z-chunks
            2);                                 // batch  => 512 blocks, 2/CU
  gme_loss_kernel<<<grid, block, 0, stream>>>(y, yp, out);
}